// Round 2
// baseline (440.380 us; speedup 1.0000x reference)
//
#include <hip/hip_runtime.h>

#define BS 16
#define TT 20
#define LL 8
#define STEPS 12
#define NN 512
#define EE 64
#define NT 32
#define PAD 68
#define HS (BS*NN*EE)   // 524288 floats per hidden buffer

#define FMA4(vr, s, W) do { \
  vr[0] = fmaf((s), (W).x, vr[0]); \
  vr[1] = fmaf((s), (W).y, vr[1]); \
  vr[2] = fmaf((s), (W).z, vr[2]); \
  vr[3] = fmaf((s), (W).w, vr[3]); } while (0)

__device__ __forceinline__ float tanh_fast(float x) {
  float t = __expf(-2.f * fabsf(x));      // e^{-2|x|} in (0,1]; no overflow
  float r = (1.f - t) / (1.f + t);
  return copysignf(r, x);
}

__device__ __forceinline__ float lrelu(float x) { return x > 0.f ? x : 0.01f * x; }

__device__ __forceinline__ float wsum64(float x) {
  #pragma unroll
  for (int off = 32; off > 0; off >>= 1) x += __shfl_xor(x, off);
  return x;
}

// ---------------------------------------------------------------------------
// Precompute: hidden0 scatter (is_last-masked label-signed embeddings) and
// expdt[b,s,l] = exp(-log(|t[b,s+l]-t[b,s+8]|+1e-6)/log 5).
// hidden0 buffer must be zeroed beforehand (memset).
// ---------------------------------------------------------------------------
__global__ __launch_bounds__(64) void precompute_kernel(
    const int* __restrict__ skill, const int* __restrict__ time_seq,
    const int* __restrict__ label, const float* __restrict__ node_emb,
    float* __restrict__ hidden0, float* __restrict__ expdt)
{
  const float INV_LOG5 = 0.6213349345596119f;  // 1/ln(5)
  int b = blockIdx.x;
  int e = threadIdx.x;
  __shared__ int s0[8];
  if (e < 8) s0[e] = skill[b*TT + e];
  __syncthreads();
  for (int l = 0; l < 8; ++l) {
    bool is_last = true;
    for (int l2 = l + 1; l2 < 8; ++l2)
      if (s0[l2] == s0[l]) is_last = false;
    if (is_last) {
      float lp = (label[b*TT + l] == 1) ? 1.f : -1.f;
      hidden0[(b*NN + s0[l])*EE + e] = node_emb[s0[l]*EE + e] * lp;
    }
  }
  for (int idx = e; idx < STEPS*LL; idx += 64) {
    int s = idx >> 3, l = idx & 7;
    float d = fabsf((float)(time_seq[b*TT + s + l] - time_seq[b*TT + s + 8]));
    expdt[(b*STEPS + s)*LL + l] = expf(-logf(d + 1e-6f) * INV_LOG5);
  }
}

// ---------------------------------------------------------------------------
// adj2 rows: rows2[k,b,t,n] = sum_m adj[k,b,skill[b,t],m]*adj[k,b,m,n] / 512
// for t in [0,19).  m is split in 4 chunks across blocks; float atomics
// accumulate (rows2 zeroed beforehand).
// ---------------------------------------------------------------------------
__global__ __launch_bounds__(256) void rows2_kernel(
    const int* __restrict__ skill, const float* __restrict__ adj,
    float* __restrict__ rows2)
{
  int bid = blockIdx.x;          // 128 blocks
  int kb  = bid >> 2;            // 0..31
  int mc  = bid & 3;
  int k = kb >> 4, b = kb & 15;
  int mbase = mc * 128;
  int tid = threadIdx.x;
  __shared__ float a_s[19*128];
  const float* A = adj + (size_t)(k*BS + b)*NN*NN;
  for (int idx = tid; idx < 19*128; idx += 256) {
    int tt = idx >> 7, mm = idx & 127;
    a_s[idx] = A[(size_t)skill[b*TT + tt]*NN + mbase + mm];
  }
  __syncthreads();
  float2 acc[19];
  #pragma unroll
  for (int tt = 0; tt < 19; ++tt) acc[tt] = make_float2(0.f, 0.f);
  int n0 = tid * 2;
  for (int mm = 0; mm < 128; ++mm) {
    float2 Av = *(const float2*)&A[(size_t)(mbase + mm)*NN + n0];
    #pragma unroll
    for (int tt = 0; tt < 19; ++tt) {
      float a = a_s[tt*128 + mm];
      acc[tt].x = fmaf(a, Av.x, acc[tt].x);
      acc[tt].y = fmaf(a, Av.y, acc[tt].y);
    }
  }
  const float sc = 1.f / 512.f;
  for (int tt = 0; tt < 19; ++tt) {
    float* dst = &rows2[((size_t)(k*BS + b)*19 + tt)*NN + n0];
    atomicAdd(dst, acc[tt].x * sc);
    atomicAdd(dst + 1, acc[tt].y * sc);
  }
}

// ---------------------------------------------------------------------------
// Per-step fused kernel.  Grid 256 = (b:16) x (ntile:16 of 32 nodes).
// Per block:
//   u[l,e]  = W1a @ hidden[b, sh[b,l]] + b1          (8 rows)
//   v[n,e]  = W1b @ hidden[b, n]                     (32-row register GEMM)
//   per l:  m1 = tanh(u+v) -> LDS; m2 = tanh(m1@W2T + b2)*ed[l];
//           agg[k,n,e] += (adj_row + adj2_row)[k,l,n] * m2
//   new_hidden = mean_k(agg);  agg rows at n==tgt[b] -> agg_tgt[t,b,k,:]
// ---------------------------------------------------------------------------
__global__ __launch_bounds__(256) void step_kernel(
    const float* __restrict__ hsrc, float* __restrict__ hdst,
    const float* __restrict__ adj, const float* __restrict__ rows2,
    const float* __restrict__ expdt, const int* __restrict__ skill,
    const float* __restrict__ W1, const float* __restrict__ b1,
    const float* __restrict__ W2, const float* __restrict__ b2,
    float* __restrict__ agg_tgt, int t)
{
  __shared__ float sW1T[64*PAD];   // w1bT[j][e]
  __shared__ float sW2T[64*PAD];   // phase A: w1aT[j][e]; phase B: w2T[j][e]
  __shared__ float sHM[NT*PAD];    // hidden tile, then m1 tile  [n][j]
  __shared__ float sHH[8*PAD];     // hh[l][j]
  __shared__ float sU[8*PAD];      // u[l][e]
  __shared__ float sCROW[2*NT];
  __shared__ float sED[8];
  __shared__ int   sSH[8];

  int tid = threadIdx.x;
  int b = blockIdx.x & 15;
  int nt = blockIdx.x >> 4;
  int nbase = nt * NT;
  int te = tid & 15, tn = tid >> 4;
  int te4 = te * 4, n2 = tn * 2;

  if (tid < 8) {
    sSH[tid] = skill[b*TT + t + tid];
    sED[tid] = expdt[(b*STEPS + t)*LL + tid];
  }
  for (int idx = tid; idx < 4096; idx += 256) {
    int e = idx >> 6, j = idx & 63;
    sW2T[j*PAD + e] = W1[e*128 + j];        // w1a (temporary residence)
    sW1T[j*PAD + e] = W1[e*128 + 64 + j];   // w1b
  }
  __syncthreads();                           // sSH ready
  for (int idx = tid; idx < 8*64; idx += 256) {
    int l = idx >> 6, j = idx & 63;
    sHH[l*PAD + j] = hsrc[(b*NN + sSH[l])*EE + j];
  }
  for (int idx = tid; idx < NT*64; idx += 256) {
    int n = idx >> 6, j = idx & 63;
    sHM[n*PAD + j] = hsrc[(b*NN + nbase + n)*EE + j];
  }
  __syncthreads();                           // sHH, sHM, sW1T, sW2T(w1a) ready

  // ---- u phase: u[l][e] = sum_j hh[l][j]*W1a[e][j] + b1[e]
  {
    int e = tid & 63, l0 = tid >> 6;         // l0 in 0..3; handles l0 and l0+4
    float a0 = 0.f, a1 = 0.f;
    #pragma unroll 8
    for (int j = 0; j < 64; ++j) {
      float w = sW2T[j*PAD + e];
      a0 = fmaf(sHH[l0*PAD + j], w, a0);
      a1 = fmaf(sHH[(l0 + 4)*PAD + j], w, a1);
    }
    float bb = b1[e];
    sU[l0*PAD + e] = a0 + bb;
    sU[(l0 + 4)*PAD + e] = a1 + bb;
  }

  // ---- GEMM1: v[n][e] = sum_j hid[n][j]*W1b[e][j]  (thread tile 2n x 4e)
  float v[2][4] = {{0,0,0,0},{0,0,0,0}};
  #pragma unroll
  for (int j = 0; j < 64; j += 4) {
    float4 a0 = *(const float4*)&sHM[n2*PAD + j];
    float4 a1 = *(const float4*)&sHM[(n2+1)*PAD + j];
    float4 w0 = *(const float4*)&sW1T[(j+0)*PAD + te4];
    float4 w1 = *(const float4*)&sW1T[(j+1)*PAD + te4];
    float4 w2v = *(const float4*)&sW1T[(j+2)*PAD + te4];
    float4 w3v = *(const float4*)&sW1T[(j+3)*PAD + te4];
    FMA4(v[0], a0.x, w0); FMA4(v[0], a0.y, w1); FMA4(v[0], a0.z, w2v); FMA4(v[0], a0.w, w3v);
    FMA4(v[1], a1.x, w0); FMA4(v[1], a1.y, w1); FMA4(v[1], a1.z, w2v); FMA4(v[1], a1.w, w3v);
  }
  __syncthreads();                           // u done; GEMM1 reads of sHM/sW2T done

  // ---- load w2T (overwrites w1a residence)
  for (int idx = tid; idx < 4096; idx += 256) {
    int e = idx >> 6, j = idx & 63;
    sW2T[j*PAD + e] = W2[e*64 + j];
  }
  float4 b2v = *(const float4*)&b2[te4];
  float b2a[4] = {b2v.x, b2v.y, b2v.z, b2v.w};

  float agg[2][2][4] = {{{0,0,0,0},{0,0,0,0}},{{0,0,0,0},{0,0,0,0}}};

  #pragma unroll 1
  for (int l = 0; l < 8; ++l) {
    // write m1 tile: m1[n][e] = tanh(u[l][e] + v[n][e])
    float4 uu = *(const float4*)&sU[l*PAD + te4];
    float ua[4] = {uu.x, uu.y, uu.z, uu.w};
    #pragma unroll
    for (int r = 0; r < 2; ++r) {
      float4 m;
      m.x = tanh_fast(ua[0] + v[r][0]);
      m.y = tanh_fast(ua[1] + v[r][1]);
      m.z = tanh_fast(ua[2] + v[r][2]);
      m.w = tanh_fast(ua[3] + v[r][3]);
      *(float4*)&sHM[(n2 + r)*PAD + te4] = m;
    }
    // stage crow[k][n] = adj[k,b,sh_l,n] + adj2row[k,b,t+l,n]
    if (tid < 64) {
      int k = tid >> 5, n = tid & 31;
      sCROW[k*NT + n] = adj[((size_t)(k*BS + b)*NN + sSH[l])*NN + nbase + n]
                      + rows2[((size_t)(k*BS + b)*19 + (t + l))*NN + nbase + n];
    }
    __syncthreads();                         // m1, crow visible (w2T done by 1st iter)

    // ---- GEMM2: m2[n][e] = sum_j m1[n][j]*W2[e][j]
    float m2[2][4] = {{0,0,0,0},{0,0,0,0}};
    #pragma unroll
    for (int j = 0; j < 64; j += 4) {
      float4 a0 = *(const float4*)&sHM[n2*PAD + j];
      float4 a1 = *(const float4*)&sHM[(n2+1)*PAD + j];
      float4 w0 = *(const float4*)&sW2T[(j+0)*PAD + te4];
      float4 w1 = *(const float4*)&sW2T[(j+1)*PAD + te4];
      float4 w2v = *(const float4*)&sW2T[(j+2)*PAD + te4];
      float4 w3v = *(const float4*)&sW2T[(j+3)*PAD + te4];
      FMA4(m2[0], a0.x, w0); FMA4(m2[0], a0.y, w1); FMA4(m2[0], a0.z, w2v); FMA4(m2[0], a0.w, w3v);
      FMA4(m2[1], a1.x, w0); FMA4(m2[1], a1.y, w1); FMA4(m2[1], a1.z, w2v); FMA4(m2[1], a1.w, w3v);
    }
    float ed = sED[l];
    float c0r0 = sCROW[n2], c0r1 = sCROW[n2 + 1];
    float c1r0 = sCROW[NT + n2], c1r1 = sCROW[NT + n2 + 1];
    #pragma unroll
    for (int cc = 0; cc < 4; ++cc) {
      float q0 = tanh_fast(m2[0][cc] + b2a[cc]) * ed;
      float q1 = tanh_fast(m2[1][cc] + b2a[cc]) * ed;
      agg[0][0][cc] = fmaf(c0r0, q0, agg[0][0][cc]);
      agg[0][1][cc] = fmaf(c0r1, q1, agg[0][1][cc]);
      agg[1][0][cc] = fmaf(c1r0, q0, agg[1][0][cc]);
      agg[1][1][cc] = fmaf(c1r1, q1, agg[1][1][cc]);
    }
    __syncthreads();                         // reads done before next l overwrites
  }

  // ---- epilogue
  int tgtn = skill[b*TT + t + 8];
  #pragma unroll
  for (int r = 0; r < 2; ++r) {
    int n = nbase + n2 + r;
    float4 nh;
    nh.x = 0.5f * (agg[0][r][0] + agg[1][r][0]);
    nh.y = 0.5f * (agg[0][r][1] + agg[1][r][1]);
    nh.z = 0.5f * (agg[0][r][2] + agg[1][r][2]);
    nh.w = 0.5f * (agg[0][r][3] + agg[1][r][3]);
    *(float4*)&hdst[(b*NN + n)*EE + te4] = nh;
    if (n == tgtn) {
      #pragma unroll
      for (int k = 0; k < 2; ++k) {
        float4 av;
        av.x = agg[k][r][0]; av.y = agg[k][r][1];
        av.z = agg[k][r][2]; av.w = agg[k][r][3];
        *(float4*)&agg_tgt[((t*BS + b)*2 + k)*EE + te4] = av;
      }
    }
  }
}

// ---------------------------------------------------------------------------
// Head: for every (step,b,k) row of agg_tgt run the 3-linear/2-layernorm
// network and emit softmax[...,1].  One wave per (step,b); k looped.
// ---------------------------------------------------------------------------
__global__ __launch_bounds__(64) void pred_kernel(
    const float* __restrict__ agg_tgt,
    const float* __restrict__ fw1, const float* __restrict__ fb1,
    const float* __restrict__ g1, const float* __restrict__ be1,
    const float* __restrict__ fw2, const float* __restrict__ fb2,
    const float* __restrict__ g2, const float* __restrict__ be2,
    const float* __restrict__ fw3, const float* __restrict__ fb3,
    float* __restrict__ out)
{
  int ts = blockIdx.x >> 4, b = blockIdx.x & 15;
  int e = threadIdx.x;
  __shared__ float sx[64];
  for (int k = 0; k < 2; ++k) {
    float x = agg_tgt[((ts*BS + b)*2 + k)*EE + e];
    sx[e] = x;
    __syncthreads();
    float y = fb1[e];
    for (int j = 0; j < 64; ++j) y = fmaf(sx[j], fw1[e*64 + j], y);
    float h1 = x + lrelu(y);
    float mean1 = wsum64(h1) * (1.f/64.f);
    float d1 = h1 - mean1;
    float var1 = wsum64(d1*d1) * (1.f/64.f);
    float xn = d1 * rsqrtf(var1 + 1e-5f) * g1[e] + be1[e];
    __syncthreads();
    sx[e] = xn;
    __syncthreads();
    float z = fb2[e];
    for (int j = 0; j < 64; ++j) z = fmaf(sx[j], fw2[e*64 + j], z);
    float h2 = h1 + lrelu(z);
    float mean2 = wsum64(h2) * (1.f/64.f);
    float d2 = h2 - mean2;
    float var2 = wsum64(d2*d2) * (1.f/64.f);
    float xn2 = d2 * rsqrtf(var2 + 1e-5f) * g2[e] + be2[e];
    float p0 = wsum64(xn2 * fw3[e]);
    float p1 = wsum64(xn2 * fw3[64 + e]);
    if (e == 0) {
      float l0 = p0 + fb3[0], l1 = p1 + fb3[1];
      out[(ts*BS + b)*2 + k] = 1.f / (1.f + expf(l0 - l1));
    }
    __syncthreads();
  }
}

extern "C" void kernel_launch(void* const* d_in, const int* in_sizes, int n_in,
                              void* d_out, int out_size, void* d_ws, size_t ws_size,
                              hipStream_t stream) {
  const int*   skill = (const int*)d_in[0];
  const int*   timeq = (const int*)d_in[1];
  const int*   label = (const int*)d_in[2];
  const float* adj   = (const float*)d_in[3];
  const float* nemb  = (const float*)d_in[4];
  const float* W1    = (const float*)d_in[5];
  const float* b1    = (const float*)d_in[6];
  const float* W2    = (const float*)d_in[7];
  const float* b2    = (const float*)d_in[8];
  const float* fw1   = (const float*)d_in[9];
  const float* fb1   = (const float*)d_in[10];
  const float* g1    = (const float*)d_in[11];
  const float* be1   = (const float*)d_in[12];
  const float* fw2   = (const float*)d_in[13];
  const float* fb2   = (const float*)d_in[14];
  const float* g2    = (const float*)d_in[15];
  const float* be2   = (const float*)d_in[16];
  const float* fw3   = (const float*)d_in[17];
  const float* fb3   = (const float*)d_in[18];
  float* out = (float*)d_out;

  float* ws      = (float*)d_ws;
  float* hbuf    = ws;                       // 2 * 524288
  float* rows2   = ws + 2*HS;                // 311296
  float* expdt   = rows2 + 2*BS*19*NN;       // 1536
  float* agg_tgt = expdt + BS*STEPS*LL;      // 24576

  (void)hipMemsetAsync(hbuf, 0, (size_t)HS * sizeof(float), stream);
  (void)hipMemsetAsync(rows2, 0, (size_t)2*BS*19*NN * sizeof(float), stream);

  precompute_kernel<<<16, 64, 0, stream>>>(skill, timeq, label, nemb, hbuf, expdt);
  rows2_kernel<<<128, 256, 0, stream>>>(skill, adj, rows2);

  for (int t = 0; t < STEPS; ++t) {
    const float* hsrc = hbuf + (size_t)(t & 1) * HS;
    float*       hdst = hbuf + (size_t)((t + 1) & 1) * HS;
    step_kernel<<<256, 256, 0, stream>>>(hsrc, hdst, adj, rows2, expdt, skill,
                                         W1, b1, W2, b2, agg_tgt, t);
  }
  pred_kernel<<<STEPS*BS, 64, 0, stream>>>(agg_tgt, fw1, fb1, g1, be1,
                                           fw2, fb2, g2, be2, fw3, fb3, out);
}

// Round 3
// 430.880 us; speedup vs baseline: 1.0220x; 1.0220x over previous
//
#include <hip/hip_runtime.h>

#define BS 16
#define TT 20
#define LL 8
#define STEPS 12
#define NN 512
#define EE 64
#define HS (BS*NN*EE)   // 524288 floats per hidden buffer

__device__ __forceinline__ float tanh_fast(float x) {
  float t = __expf(-2.f * fabsf(x));      // e^{-2|x|} in (0,1]; no overflow
  float r = (1.f - t) / (1.f + t);
  return copysignf(r, x);
}

__device__ __forceinline__ float lrelu(float x) { return x > 0.f ? x : 0.01f * x; }

__device__ __forceinline__ float wsum64(float x) {
  #pragma unroll
  for (int off = 32; off > 0; off >>= 1) x += __shfl_xor(x, off);
  return x;
}

// ---------------------------------------------------------------------------
// Precompute: hidden0 scatter (is_last-masked label-signed embeddings) and
// expdt[b,s,l] = exp(-log(|t[b,s+l]-t[b,s+8]|+1e-6)/log 5).
// hidden0 buffer must be zeroed beforehand (memset).
// ---------------------------------------------------------------------------
__global__ __launch_bounds__(64) void precompute_kernel(
    const int* __restrict__ skill, const int* __restrict__ time_seq,
    const int* __restrict__ label, const float* __restrict__ node_emb,
    float* __restrict__ hidden0, float* __restrict__ expdt)
{
  const float INV_LOG5 = 0.6213349345596119f;  // 1/ln(5)
  int b = blockIdx.x;
  int e = threadIdx.x;
  __shared__ int s0[8];
  if (e < 8) s0[e] = skill[b*TT + e];
  __syncthreads();
  for (int l = 0; l < 8; ++l) {
    bool is_last = true;
    for (int l2 = l + 1; l2 < 8; ++l2)
      if (s0[l2] == s0[l]) is_last = false;
    if (is_last) {
      float lp = (label[b*TT + l] == 1) ? 1.f : -1.f;
      hidden0[(b*NN + s0[l])*EE + e] = node_emb[s0[l]*EE + e] * lp;
    }
  }
  for (int idx = e; idx < STEPS*LL; idx += 64) {
    int s = idx >> 3, l = idx & 7;
    float d = fabsf((float)(time_seq[b*TT + s + l] - time_seq[b*TT + s + 8]));
    expdt[(b*STEPS + s)*LL + l] = expf(-logf(d + 1e-6f) * INV_LOG5);
  }
}

// ---------------------------------------------------------------------------
// adj2 rows: rows2[k,b,t,n] = sum_m adj[k,b,skill[b,t],m]*adj[k,b,m,n] / 512
// for t in [0,19).  m split in 16 chunks of 32 across blocks (512 blocks ->
// 2/CU); float atomics accumulate (rows2 zeroed beforehand).
// ---------------------------------------------------------------------------
__global__ __launch_bounds__(256) void rows2_kernel(
    const int* __restrict__ skill, const float* __restrict__ adj,
    float* __restrict__ rows2)
{
  int bid = blockIdx.x;          // 512 blocks
  int kb  = bid >> 4;            // 0..31
  int mc  = bid & 15;
  int k = kb >> 4, b = kb & 15;
  int mbase = mc * 32;
  int tid = threadIdx.x;
  __shared__ float a_s[19*32];
  const float* A = adj + (size_t)(k*BS + b)*NN*NN;
  for (int idx = tid; idx < 19*32; idx += 256) {
    int tt = idx >> 5, mm = idx & 31;
    a_s[idx] = A[(size_t)skill[b*TT + tt]*NN + mbase + mm];
  }
  __syncthreads();
  float2 acc[19];
  #pragma unroll
  for (int tt = 0; tt < 19; ++tt) acc[tt] = make_float2(0.f, 0.f);
  int n0 = tid * 2;
  #pragma unroll 4
  for (int mm = 0; mm < 32; ++mm) {
    float2 Av = *(const float2*)&A[(size_t)(mbase + mm)*NN + n0];
    #pragma unroll
    for (int tt = 0; tt < 19; ++tt) {
      float a = a_s[tt*32 + mm];
      acc[tt].x = fmaf(a, Av.x, acc[tt].x);
      acc[tt].y = fmaf(a, Av.y, acc[tt].y);
    }
  }
  const float sc = 1.f / 512.f;
  #pragma unroll
  for (int tt = 0; tt < 19; ++tt) {
    float* dst = &rows2[((size_t)(k*BS + b)*19 + tt)*NN + n0];
    atomicAdd(dst, acc[tt].x * sc);
    atomicAdd(dst + 1, acc[tt].y * sc);
  }
}

// ---------------------------------------------------------------------------
// Per-step fused kernel v2.  Grid 512 = (b:16) x (ntile:32 of 16 nodes).
// Single l-batched GEMM2 (thread tile 8l x 1n x 4e); m1 staged once in LDS.
// LDS 62KB via phase aliasing -> 2 blocks/CU.  4 syncthreads total.
// ---------------------------------------------------------------------------
__global__ __launch_bounds__(256) void step_kernel(
    const float* __restrict__ hsrc, float* __restrict__ hdst,
    const float* __restrict__ adj, const float* __restrict__ rows2,
    const float* __restrict__ expdt, const int* __restrict__ skill,
    const float* __restrict__ W1, const float* __restrict__ b1,
    const float* __restrict__ W2, const float* __restrict__ b2,
    float* __restrict__ agg_tgt, int t)
{
  // phase A: {W1aT, W1bT, Hid, HH} ; phase B: sM1 (aliased)
  __shared__ float sBig[10336];
  __shared__ float sW2T[64*68];      // survives both phases
  __shared__ float sU[8*68];
  __shared__ float sCROW[2*8*16];    // [k][l][n]
  __shared__ float sED[8];
  __shared__ int   sSH[8];

  float* sW1aT = sBig;               // 64*68 = 4352
  float* sW1bT = sBig + 4352;        // 64*68
  float* sHid  = sBig + 8704;        // 16*68 = 1088
  float* sHH   = sBig + 9792;        // 8*68 = 544   (ends at 10336)
  float* sM1   = sBig;               // 128*68 = 8704 (phase B)

  int tid = threadIdx.x;
  int b  = blockIdx.x & 15;
  int nt = blockIdx.x >> 4;
  int nbase = nt * 16;

  if (tid < 8) {
    sSH[tid] = skill[b*TT + t + tid];
    sED[tid] = expdt[(b*STEPS + t)*LL + tid];
  }
  // stage weights transposed: wT[j][e]
  for (int idx = tid; idx < 4096; idx += 256) {
    int e = idx >> 6, j = idx & 63;
    sW1aT[j*68 + e] = W1[e*128 + j];
    sW1bT[j*68 + e] = W1[e*128 + 64 + j];
    sW2T [j*68 + e] = W2[e*64 + j];
  }
  __syncthreads();                   // sSH visible

  // stage hidden tile, hh, crow
  for (int idx = tid; idx < 256; idx += 256) {
    int n = idx >> 4, jc = (idx & 15) * 4;
    *(float4*)&sHid[n*68 + jc] = *(const float4*)&hsrc[(b*NN + nbase + n)*EE + jc];
  }
  if (tid < 128) {
    int l = tid >> 4, jc = (tid & 15) * 4;
    *(float4*)&sHH[l*68 + jc] = *(const float4*)&hsrc[(b*NN + sSH[l])*EE + jc];
  }
  {
    int k = tid >> 7, l = (tid >> 4) & 7, n = tid & 15;
    sCROW[tid] = adj[((size_t)(k*BS + b)*NN + sSH[l])*NN + nbase + n]
               + rows2[((size_t)(k*BS + b)*19 + (t + l))*NN + nbase + n];
  }
  __syncthreads();                   // phase-A LDS ready

  // ---- GEMM1 (v, tile 1n x 4e) fused with u (waves 0-1: tn<8)
  int te = tid & 15, tn = tid >> 4;
  int te4 = te * 4;
  float v0=0.f, v1=0.f, v2=0.f, v3=0.f;
  float u0=0.f, u1=0.f, u2=0.f, u3=0.f;
  #pragma unroll
  for (int j = 0; j < 64; j += 4) {
    float4 a  = *(const float4*)&sHid[tn*68 + j];
    float4 w0 = *(const float4*)&sW1bT[(j+0)*68 + te4];
    float4 w1 = *(const float4*)&sW1bT[(j+1)*68 + te4];
    float4 w2 = *(const float4*)&sW1bT[(j+2)*68 + te4];
    float4 w3 = *(const float4*)&sW1bT[(j+3)*68 + te4];
    v0 = fmaf(a.x,w0.x, fmaf(a.y,w1.x, fmaf(a.z,w2.x, fmaf(a.w,w3.x, v0))));
    v1 = fmaf(a.x,w0.y, fmaf(a.y,w1.y, fmaf(a.z,w2.y, fmaf(a.w,w3.y, v1))));
    v2 = fmaf(a.x,w0.z, fmaf(a.y,w1.z, fmaf(a.z,w2.z, fmaf(a.w,w3.z, v2))));
    v3 = fmaf(a.x,w0.w, fmaf(a.y,w1.w, fmaf(a.z,w2.w, fmaf(a.w,w3.w, v3))));
    if (tn < 8) {                    // wave-uniform (waves 0,1)
      float4 ah = *(const float4*)&sHH[tn*68 + j];
      float4 q0 = *(const float4*)&sW1aT[(j+0)*68 + te4];
      float4 q1 = *(const float4*)&sW1aT[(j+1)*68 + te4];
      float4 q2 = *(const float4*)&sW1aT[(j+2)*68 + te4];
      float4 q3 = *(const float4*)&sW1aT[(j+3)*68 + te4];
      u0 = fmaf(ah.x,q0.x, fmaf(ah.y,q1.x, fmaf(ah.z,q2.x, fmaf(ah.w,q3.x, u0))));
      u1 = fmaf(ah.x,q0.y, fmaf(ah.y,q1.y, fmaf(ah.z,q2.y, fmaf(ah.w,q3.y, u1))));
      u2 = fmaf(ah.x,q0.z, fmaf(ah.y,q1.z, fmaf(ah.z,q2.z, fmaf(ah.w,q3.z, u2))));
      u3 = fmaf(ah.x,q0.w, fmaf(ah.y,q1.w, fmaf(ah.z,q2.w, fmaf(ah.w,q3.w, u3))));
    }
  }
  if (tn < 8) {
    float4 bb = *(const float4*)&b1[te4];
    float4 uu; uu.x = u0 + bb.x; uu.y = u1 + bb.y; uu.z = u2 + bb.z; uu.w = u3 + bb.w;
    *(float4*)&sU[tn*68 + te4] = uu;
  }
  __syncthreads();                   // u visible; phase-A reads done -> sM1 may overwrite

  // ---- m1[l][n][e] = tanh(u[l][e] + v[n][e])  (n = tn here)
  #pragma unroll
  for (int l = 0; l < 8; ++l) {
    float4 uu = *(const float4*)&sU[l*68 + te4];
    float4 m;
    m.x = tanh_fast(uu.x + v0);
    m.y = tanh_fast(uu.y + v1);
    m.z = tanh_fast(uu.z + v2);
    m.w = tanh_fast(uu.w + v3);
    *(float4*)&sM1[(l*16 + tn)*68 + te4] = m;
  }
  __syncthreads();                   // m1 ready

  // ---- GEMM2, l-batched: acc[l][e] = sum_j m1[l][n][j] * W2[e][j]
  int n = tid & 15, eg = tid >> 4;
  int e0 = eg * 4;
  float acc[8][4];
  #pragma unroll
  for (int l = 0; l < 8; ++l)
    acc[l][0] = acc[l][1] = acc[l][2] = acc[l][3] = 0.f;
  #pragma unroll
  for (int j = 0; j < 64; j += 4) {
    float4 w0 = *(const float4*)&sW2T[(j+0)*68 + e0];
    float4 w1 = *(const float4*)&sW2T[(j+1)*68 + e0];
    float4 w2 = *(const float4*)&sW2T[(j+2)*68 + e0];
    float4 w3 = *(const float4*)&sW2T[(j+3)*68 + e0];
    float4 a[8];
    #pragma unroll
    for (int l = 0; l < 8; ++l) a[l] = *(const float4*)&sM1[(l*16 + n)*68 + j];
    #pragma unroll
    for (int l = 0; l < 8; ++l) {
      acc[l][0] = fmaf(a[l].x,w0.x, fmaf(a[l].y,w1.x, fmaf(a[l].z,w2.x, fmaf(a[l].w,w3.x, acc[l][0]))));
      acc[l][1] = fmaf(a[l].x,w0.y, fmaf(a[l].y,w1.y, fmaf(a[l].z,w2.y, fmaf(a[l].w,w3.y, acc[l][1]))));
      acc[l][2] = fmaf(a[l].x,w0.z, fmaf(a[l].y,w1.z, fmaf(a[l].z,w2.z, fmaf(a[l].w,w3.z, acc[l][2]))));
      acc[l][3] = fmaf(a[l].x,w0.w, fmaf(a[l].y,w1.w, fmaf(a[l].z,w2.w, fmaf(a[l].w,w3.w, acc[l][3]))));
    }
  }

  // ---- m2 = tanh(acc + b2)*ed ; agg[k] += crow[k][l][n]*m2, summed over l
  float4 bb2 = *(const float4*)&b2[e0];
  float ag0[4] = {0.f,0.f,0.f,0.f};
  float ag1[4] = {0.f,0.f,0.f,0.f};
  #pragma unroll
  for (int l = 0; l < 8; ++l) {
    float ed = sED[l];
    float c0 = sCROW[l*16 + n];
    float c1 = sCROW[128 + l*16 + n];
    float q0 = tanh_fast(acc[l][0] + bb2.x) * ed;
    float q1 = tanh_fast(acc[l][1] + bb2.y) * ed;
    float q2 = tanh_fast(acc[l][2] + bb2.z) * ed;
    float q3 = tanh_fast(acc[l][3] + bb2.w) * ed;
    ag0[0] = fmaf(c0,q0,ag0[0]); ag1[0] = fmaf(c1,q0,ag1[0]);
    ag0[1] = fmaf(c0,q1,ag0[1]); ag1[1] = fmaf(c1,q1,ag1[1]);
    ag0[2] = fmaf(c0,q2,ag0[2]); ag1[2] = fmaf(c1,q2,ag1[2]);
    ag0[3] = fmaf(c0,q3,ag0[3]); ag1[3] = fmaf(c1,q3,ag1[3]);
  }

  // ---- epilogue: new_hidden = mean_k(agg); tgt rows to agg_tgt
  int nn_ = nbase + n;
  float4 h;
  h.x = 0.5f*(ag0[0]+ag1[0]);
  h.y = 0.5f*(ag0[1]+ag1[1]);
  h.z = 0.5f*(ag0[2]+ag1[2]);
  h.w = 0.5f*(ag0[3]+ag1[3]);
  *(float4*)&hdst[(b*NN + nn_)*EE + e0] = h;
  if (nn_ == skill[b*TT + t + 8]) {
    float4 A0; A0.x = ag0[0]; A0.y = ag0[1]; A0.z = ag0[2]; A0.w = ag0[3];
    float4 A1; A1.x = ag1[0]; A1.y = ag1[1]; A1.z = ag1[2]; A1.w = ag1[3];
    *(float4*)&agg_tgt[((t*BS + b)*2 + 0)*EE + e0] = A0;
    *(float4*)&agg_tgt[((t*BS + b)*2 + 1)*EE + e0] = A1;
  }
}

// ---------------------------------------------------------------------------
// Head: for every (step,b,k) row of agg_tgt run the 3-linear/2-layernorm
// network and emit softmax[...,1].  One wave per (step,b); k looped.
// ---------------------------------------------------------------------------
__global__ __launch_bounds__(64) void pred_kernel(
    const float* __restrict__ agg_tgt,
    const float* __restrict__ fw1, const float* __restrict__ fb1,
    const float* __restrict__ g1, const float* __restrict__ be1,
    const float* __restrict__ fw2, const float* __restrict__ fb2,
    const float* __restrict__ g2, const float* __restrict__ be2,
    const float* __restrict__ fw3, const float* __restrict__ fb3,
    float* __restrict__ out)
{
  int ts = blockIdx.x >> 4, b = blockIdx.x & 15;
  int e = threadIdx.x;
  __shared__ float sx[64];
  for (int k = 0; k < 2; ++k) {
    float x = agg_tgt[((ts*BS + b)*2 + k)*EE + e];
    sx[e] = x;
    __syncthreads();
    float y = fb1[e];
    for (int j = 0; j < 64; ++j) y = fmaf(sx[j], fw1[e*64 + j], y);
    float h1 = x + lrelu(y);
    float mean1 = wsum64(h1) * (1.f/64.f);
    float d1 = h1 - mean1;
    float var1 = wsum64(d1*d1) * (1.f/64.f);
    float xn = d1 * rsqrtf(var1 + 1e-5f) * g1[e] + be1[e];
    __syncthreads();
    sx[e] = xn;
    __syncthreads();
    float z = fb2[e];
    for (int j = 0; j < 64; ++j) z = fmaf(sx[j], fw2[e*64 + j], z);
    float h2 = h1 + lrelu(z);
    float mean2 = wsum64(h2) * (1.f/64.f);
    float d2 = h2 - mean2;
    float var2 = wsum64(d2*d2) * (1.f/64.f);
    float xn2 = d2 * rsqrtf(var2 + 1e-5f) * g2[e] + be2[e];
    float p0 = wsum64(xn2 * fw3[e]);
    float p1 = wsum64(xn2 * fw3[64 + e]);
    if (e == 0) {
      float l0 = p0 + fb3[0], l1 = p1 + fb3[1];
      out[(ts*BS + b)*2 + k] = 1.f / (1.f + expf(l0 - l1));
    }
    __syncthreads();
  }
}

extern "C" void kernel_launch(void* const* d_in, const int* in_sizes, int n_in,
                              void* d_out, int out_size, void* d_ws, size_t ws_size,
                              hipStream_t stream) {
  const int*   skill = (const int*)d_in[0];
  const int*   timeq = (const int*)d_in[1];
  const int*   label = (const int*)d_in[2];
  const float* adj   = (const float*)d_in[3];
  const float* nemb  = (const float*)d_in[4];
  const float* W1    = (const float*)d_in[5];
  const float* b1    = (const float*)d_in[6];
  const float* W2    = (const float*)d_in[7];
  const float* b2    = (const float*)d_in[8];
  const float* fw1   = (const float*)d_in[9];
  const float* fb1   = (const float*)d_in[10];
  const float* g1    = (const float*)d_in[11];
  const float* be1   = (const float*)d_in[12];
  const float* fw2   = (const float*)d_in[13];
  const float* fb2   = (const float*)d_in[14];
  const float* g2    = (const float*)d_in[15];
  const float* be2   = (const float*)d_in[16];
  const float* fw3   = (const float*)d_in[17];
  const float* fb3   = (const float*)d_in[18];
  float* out = (float*)d_out;

  float* ws      = (float*)d_ws;
  float* hbuf    = ws;                       // 2 * 524288
  float* rows2   = ws + 2*HS;                // 311296
  float* expdt   = rows2 + 2*BS*19*NN;       // 1536
  float* agg_tgt = expdt + BS*STEPS*LL;      // 24576

  (void)hipMemsetAsync(hbuf, 0, (size_t)HS * sizeof(float), stream);
  (void)hipMemsetAsync(rows2, 0, (size_t)2*BS*19*NN * sizeof(float), stream);

  precompute_kernel<<<16, 64, 0, stream>>>(skill, timeq, label, nemb, hbuf, expdt);
  rows2_kernel<<<512, 256, 0, stream>>>(skill, adj, rows2);

  for (int t = 0; t < STEPS; ++t) {
    const float* hsrc = hbuf + (size_t)(t & 1) * HS;
    float*       hdst = hbuf + (size_t)((t + 1) & 1) * HS;
    step_kernel<<<512, 256, 0, stream>>>(hsrc, hdst, adj, rows2, expdt, skill,
                                         W1, b1, W2, b2, agg_tgt, t);
  }
  pred_kernel<<<STEPS*BS, 64, 0, stream>>>(agg_tgt, fw1, fb1, g1, be1,
                                           fw2, fb2, g2, be2, fw3, fb3, out);
}

// Round 4
// 261.468 us; speedup vs baseline: 1.6843x; 1.6479x over previous
//
#include <hip/hip_runtime.h>

#define BS 16
#define TT 20
#define LL 8
#define STEPS 12
#define NN 512
#define EE 64
#define HS (BS*NN*EE)   // 524288 floats per hidden buffer
#define NPART 311296    // 2*16*19*512

typedef __attribute__((ext_vector_type(8))) short bfrag8;
typedef __attribute__((ext_vector_type(4))) float f32x4;
typedef unsigned short ushort_t;
typedef unsigned int uint_t;

#define MFMA16(a,b,c) __builtin_amdgcn_mfma_f32_16x16x32_bf16(a,b,c,0,0,0)

__device__ __forceinline__ float tanh_fast(float x) {
  float t = __expf(-2.f * fabsf(x));      // e^{-2|x|} in (0,1]; no overflow
  float r = (1.f - t) / (1.f + t);
  return copysignf(r, x);
}

__device__ __forceinline__ float lrelu(float x) { return x > 0.f ? x : 0.01f * x; }

__device__ __forceinline__ float wsum64(float x) {
  #pragma unroll
  for (int off = 32; off > 0; off >>= 1) x += __shfl_xor(x, off);
  return x;
}

__device__ __forceinline__ ushort_t f2bf(float f) {   // RNE float->bf16
  uint_t u = __float_as_uint(f);
  u += 0x7fffu + ((u >> 16) & 1u);
  return (ushort_t)(u >> 16);
}

// ---------------------------------------------------------------------------
// Precompute: hidden0 scatter + expdt table.  hidden0 zeroed beforehand.
// ---------------------------------------------------------------------------
__global__ __launch_bounds__(64) void precompute_kernel(
    const int* __restrict__ skill, const int* __restrict__ time_seq,
    const int* __restrict__ label, const float* __restrict__ node_emb,
    float* __restrict__ hidden0, float* __restrict__ expdt)
{
  const float INV_LOG5 = 0.6213349345596119f;  // 1/ln(5)
  int b = blockIdx.x;
  int e = threadIdx.x;
  __shared__ int s0[8];
  if (e < 8) s0[e] = skill[b*TT + e];
  __syncthreads();
  for (int l = 0; l < 8; ++l) {
    bool is_last = true;
    for (int l2 = l + 1; l2 < 8; ++l2)
      if (s0[l2] == s0[l]) is_last = false;
    if (is_last) {
      float lp = (label[b*TT + l] == 1) ? 1.f : -1.f;
      hidden0[(b*NN + s0[l])*EE + e] = node_emb[s0[l]*EE + e] * lp;
    }
  }
  for (int idx = e; idx < STEPS*LL; idx += 64) {
    int s = idx >> 3, l = idx & 7;
    float d = fabsf((float)(time_seq[b*TT + s + l] - time_seq[b*TT + s + 8]));
    expdt[(b*STEPS + s)*LL + l] = expf(-logf(d + 1e-6f) * INV_LOG5);
  }
}

// ---------------------------------------------------------------------------
// rows2 pass1: partial[mc][kb][t][n] = sum_{m in chunk mc} a[t,m]*A[m,n]
// grid 256 = kb(32) x mc(8), m-chunk 64.  Plain stores, no atomics.
// ---------------------------------------------------------------------------
__global__ __launch_bounds__(256) void rows2_p1_kernel(
    const int* __restrict__ skill, const float* __restrict__ adj,
    float* __restrict__ partial)
{
  int kb = blockIdx.x >> 3;      // 0..31 == (k*16+b)
  int mc = blockIdx.x & 7;
  int b = kb & 15;
  int m0 = mc * 64;
  int tid = threadIdx.x;
  __shared__ float a_s[19*64];
  const float* A = adj + (size_t)kb*NN*NN;
  for (int idx = tid; idx < 19*64; idx += 256) {
    int tt = idx >> 6, mm = idx & 63;
    a_s[idx] = A[(size_t)skill[b*TT + tt]*NN + m0 + mm];
  }
  __syncthreads();
  float2 acc[19];
  #pragma unroll
  for (int tt = 0; tt < 19; ++tt) acc[tt] = make_float2(0.f, 0.f);
  int n0 = tid * 2;
  for (int mm0 = 0; mm0 < 64; mm0 += 8) {
    float2 v[8];
    #pragma unroll
    for (int i = 0; i < 8; ++i)
      v[i] = *(const float2*)&A[(size_t)(m0 + mm0 + i)*NN + n0];
    #pragma unroll
    for (int tt = 0; tt < 19; ++tt) {
      float4 aa = *(const float4*)&a_s[tt*64 + mm0];
      float4 ab = *(const float4*)&a_s[tt*64 + mm0 + 4];
      acc[tt].x = fmaf(aa.x, v[0].x, acc[tt].x); acc[tt].y = fmaf(aa.x, v[0].y, acc[tt].y);
      acc[tt].x = fmaf(aa.y, v[1].x, acc[tt].x); acc[tt].y = fmaf(aa.y, v[1].y, acc[tt].y);
      acc[tt].x = fmaf(aa.z, v[2].x, acc[tt].x); acc[tt].y = fmaf(aa.z, v[2].y, acc[tt].y);
      acc[tt].x = fmaf(aa.w, v[3].x, acc[tt].x); acc[tt].y = fmaf(aa.w, v[3].y, acc[tt].y);
      acc[tt].x = fmaf(ab.x, v[4].x, acc[tt].x); acc[tt].y = fmaf(ab.x, v[4].y, acc[tt].y);
      acc[tt].x = fmaf(ab.y, v[5].x, acc[tt].x); acc[tt].y = fmaf(ab.y, v[5].y, acc[tt].y);
      acc[tt].x = fmaf(ab.z, v[6].x, acc[tt].x); acc[tt].y = fmaf(ab.z, v[6].y, acc[tt].y);
      acc[tt].x = fmaf(ab.w, v[7].x, acc[tt].x); acc[tt].y = fmaf(ab.w, v[7].y, acc[tt].y);
    }
  }
  #pragma unroll
  for (int tt = 0; tt < 19; ++tt)
    *(float2*)&partial[((size_t)mc*32*19 + (size_t)kb*19 + tt)*NN + n0] = acc[tt];
}

// rows2 pass2: reduce 8 m-chunks, scale by 1/512.
__global__ __launch_bounds__(256) void rows2_p2_kernel(
    const float* __restrict__ partial, float* __restrict__ rows2)
{
  int idx = blockIdx.x * 256 + threadIdx.x;
  if (idx >= NPART) return;
  float s = 0.f;
  #pragma unroll
  for (int mc = 0; mc < 8; ++mc) s += partial[(size_t)mc*NPART + idx];
  rows2[idx] = s * (1.f/512.f);
}

// ---------------------------------------------------------------------------
// Per-step fused kernel v3 (MFMA).  Grid 512 = (b:16) x (ntile:32 of 16 n).
// bf16 LDS (stride 72 = 144B, 16B-aligned, uniform bank phase).
// GEMM1: v[16n x 64e] and u[8l x 64e] via mfma_f32_16x16x32_bf16.
// m1 = tanh(u+v) -> bf16 LDS (aliases dead W1a/W1b region).
// GEMM2: m2[128(l,n) x 64e]; epilogue tanh*ed, crow-weighted agg, mean_k.
// ---------------------------------------------------------------------------
__global__ __launch_bounds__(256) void step_kernel(
    const float* __restrict__ hsrc, float* __restrict__ hdst,
    const float* __restrict__ adj, const float* __restrict__ rows2,
    const float* __restrict__ expdt, const int* __restrict__ skill,
    const float* __restrict__ W1, const float* __restrict__ b1,
    const float* __restrict__ W2, const float* __restrict__ b2,
    float* __restrict__ agg_tgt, int t)
{
  __shared__ __align__(16) ushort_t sWab[9216];  // Wa[64x72] | Wb[64x72]; aliased by sM1[128x72]
  __shared__ __align__(16) ushort_t sW2[4608];   // W2[64x72]
  __shared__ __align__(16) ushort_t sHid[1152];  // 16x72
  __shared__ __align__(16) ushort_t sHH[1152];   // 16x72 (rows 8..15 zero)
  __shared__ float sU[8*68];
  __shared__ float sCROW[256];                   // [k][l][n]
  __shared__ float sED[8];

  ushort_t* sWa = sWab;
  ushort_t* sWb = sWab + 64*72;
  ushort_t* sM1 = sWab;                          // phase B alias

  int tid = threadIdx.x;
  int b  = blockIdx.x & 15;
  int nt = blockIdx.x >> 4;
  int nbase = nt * 16;

  if (tid < 8) sED[tid] = expdt[(b*STEPS + t)*LL + tid];

  // weights -> bf16 LDS
  for (int idx = tid; idx < 4096; idx += 256) {
    int e = idx >> 6, j = idx & 63;
    sWa[e*72 + j] = f2bf(W1[e*128 + j]);
    sWb[e*72 + j] = f2bf(W1[e*128 + 64 + j]);
    sW2[e*72 + j] = f2bf(W2[e*64 + j]);
  }
  // hidden tile (16 n) -> bf16
  for (int idx = tid; idx < 1024; idx += 256) {
    int n = idx >> 6, j = idx & 63;
    sHid[n*72 + j] = f2bf(hsrc[(b*NN + nbase + n)*EE + j]);
  }
  // hh (8 rows, zero-pad to 16) -> bf16
  for (int idx = tid; idx < 1024; idx += 256) {
    int l = idx >> 6, j = idx & 63;
    ushort_t v = 0;
    if (l < 8) {
      int sh = skill[b*TT + t + l];
      v = f2bf(hsrc[(b*NN + sh)*EE + j]);
    }
    sHH[l*72 + j] = v;
  }
  // crow[k][l][n]
  {
    int k = tid >> 7, l = (tid >> 4) & 7, n = tid & 15;
    int sh = skill[b*TT + t + l];
    sCROW[tid] = adj[((size_t)(k*BS + b)*NN + sh)*NN + nbase + n]
               + rows2[((size_t)(k*BS + b)*19 + (t + l))*NN + nbase + n];
  }
  __syncthreads();

  int lane = tid & 63;
  int w = tid >> 6;                 // wave id 0..3 -> e-col-tile
  int q = lane >> 4, nn = lane & 15;
  int ec = w * 16;
  int epos = ec + nn;               // this lane's output-feature column

  // ---- GEMM1: v (Hid @ W1b^T) and u (HH @ W1a^T), one col-tile per wave
  f32x4 accV = {0.f,0.f,0.f,0.f}, accU = {0.f,0.f,0.f,0.f};
  {
    bfrag8 a0 = *(const bfrag8*)&sHid[nn*72 + q*8];
    bfrag8 a1 = *(const bfrag8*)&sHid[nn*72 + 32 + q*8];
    bfrag8 b0 = *(const bfrag8*)&sWb[epos*72 + q*8];
    bfrag8 b1f = *(const bfrag8*)&sWb[epos*72 + 32 + q*8];
    accV = MFMA16(a0, b0, accV);
    accV = MFMA16(a1, b1f, accV);
    bfrag8 h0 = *(const bfrag8*)&sHH[nn*72 + q*8];
    bfrag8 h1 = *(const bfrag8*)&sHH[nn*72 + 32 + q*8];
    bfrag8 c0 = *(const bfrag8*)&sWa[epos*72 + q*8];
    bfrag8 c1 = *(const bfrag8*)&sWa[epos*72 + 32 + q*8];
    accU = MFMA16(h0, c0, accU);
    accU = MFMA16(h1, c1, accU);
  }
  if (q < 2) {                      // D rows q*4+r = l in 0..7
    float bb = b1[epos];
    #pragma unroll
    for (int r = 0; r < 4; ++r)
      sU[(q*4 + r)*68 + epos] = accU[r] + bb;
  }
  __syncthreads();                  // sU done; GEMM1 LDS reads done -> alias safe

  // ---- m1[l*16+m][e] = tanh(u[l][e] + v[m][e]) -> bf16 (m = q*4+r)
  #pragma unroll
  for (int l = 0; l < 8; ++l) {
    float uu = sU[l*68 + epos];
    #pragma unroll
    for (int r = 0; r < 4; ++r)
      sM1[(l*16 + q*4 + r)*72 + epos] = f2bf(tanh_fast(uu + accV[r]));
  }
  __syncthreads();                  // m1 ready

  // ---- GEMM2: m2 = m1 @ W2^T (8 row-tiles = l, one col-tile per wave)
  f32x4 acc2[8];
  #pragma unroll
  for (int l = 0; l < 8; ++l) acc2[l] = (f32x4){0.f,0.f,0.f,0.f};
  {
    bfrag8 w0 = *(const bfrag8*)&sW2[epos*72 + q*8];
    bfrag8 w1 = *(const bfrag8*)&sW2[epos*72 + 32 + q*8];
    #pragma unroll
    for (int l = 0; l < 8; ++l) {
      bfrag8 a0 = *(const bfrag8*)&sM1[(l*16 + nn)*72 + q*8];
      bfrag8 a1 = *(const bfrag8*)&sM1[(l*16 + nn)*72 + 32 + q*8];
      acc2[l] = MFMA16(a0, w0, acc2[l]);
      acc2[l] = MFMA16(a1, w1, acc2[l]);
    }
  }

  // ---- epilogue: q2 = tanh(m2+b2)*ed; agg_k += crow[k][l][m]*q2; mean_k
  float b2v = b2[epos];
  float ag0[4] = {0.f,0.f,0.f,0.f};
  float ag1[4] = {0.f,0.f,0.f,0.f};
  #pragma unroll
  for (int l = 0; l < 8; ++l) {
    float ed = sED[l];
    #pragma unroll
    for (int r = 0; r < 4; ++r) {
      int m = q*4 + r;
      float qv = tanh_fast(acc2[l][r] + b2v) * ed;
      ag0[r] = fmaf(sCROW[l*16 + m], qv, ag0[r]);
      ag1[r] = fmaf(sCROW[128 + l*16 + m], qv, ag1[r]);
    }
  }
  int tgtn = skill[b*TT + t + 8];
  #pragma unroll
  for (int r = 0; r < 4; ++r) {
    int node = nbase + q*4 + r;
    hdst[(b*NN + node)*EE + epos] = 0.5f * (ag0[r] + ag1[r]);
    if (node == tgtn) {
      agg_tgt[((t*BS + b)*2 + 0)*EE + epos] = ag0[r];
      agg_tgt[((t*BS + b)*2 + 1)*EE + epos] = ag1[r];
    }
  }
}

// ---------------------------------------------------------------------------
// Head: 3 linears + 2 layernorms + softmax[...,1] on the 384 gathered rows.
// ---------------------------------------------------------------------------
__global__ __launch_bounds__(64) void pred_kernel(
    const float* __restrict__ agg_tgt,
    const float* __restrict__ fw1, const float* __restrict__ fb1,
    const float* __restrict__ g1, const float* __restrict__ be1,
    const float* __restrict__ fw2, const float* __restrict__ fb2,
    const float* __restrict__ g2, const float* __restrict__ be2,
    const float* __restrict__ fw3, const float* __restrict__ fb3,
    float* __restrict__ out)
{
  int ts = blockIdx.x >> 4, b = blockIdx.x & 15;
  int e = threadIdx.x;
  __shared__ float sx[64];
  for (int k = 0; k < 2; ++k) {
    float x = agg_tgt[((ts*BS + b)*2 + k)*EE + e];
    sx[e] = x;
    __syncthreads();
    float y = fb1[e];
    for (int j = 0; j < 64; ++j) y = fmaf(sx[j], fw1[e*64 + j], y);
    float h1 = x + lrelu(y);
    float mean1 = wsum64(h1) * (1.f/64.f);
    float d1 = h1 - mean1;
    float var1 = wsum64(d1*d1) * (1.f/64.f);
    float xn = d1 * rsqrtf(var1 + 1e-5f) * g1[e] + be1[e];
    __syncthreads();
    sx[e] = xn;
    __syncthreads();
    float z = fb2[e];
    for (int j = 0; j < 64; ++j) z = fmaf(sx[j], fw2[e*64 + j], z);
    float h2 = h1 + lrelu(z);
    float mean2 = wsum64(h2) * (1.f/64.f);
    float d2 = h2 - mean2;
    float var2 = wsum64(d2*d2) * (1.f/64.f);
    float xn2 = d2 * rsqrtf(var2 + 1e-5f) * g2[e] + be2[e];
    float p0 = wsum64(xn2 * fw3[e]);
    float p1 = wsum64(xn2 * fw3[64 + e]);
    if (e == 0) {
      float l0 = p0 + fb3[0], l1 = p1 + fb3[1];
      out[(ts*BS + b)*2 + k] = 1.f / (1.f + expf(l0 - l1));
    }
    __syncthreads();
  }
}

extern "C" void kernel_launch(void* const* d_in, const int* in_sizes, int n_in,
                              void* d_out, int out_size, void* d_ws, size_t ws_size,
                              hipStream_t stream) {
  const int*   skill = (const int*)d_in[0];
  const int*   timeq = (const int*)d_in[1];
  const int*   label = (const int*)d_in[2];
  const float* adj   = (const float*)d_in[3];
  const float* nemb  = (const float*)d_in[4];
  const float* W1    = (const float*)d_in[5];
  const float* b1    = (const float*)d_in[6];
  const float* W2    = (const float*)d_in[7];
  const float* b2    = (const float*)d_in[8];
  const float* fw1   = (const float*)d_in[9];
  const float* fb1   = (const float*)d_in[10];
  const float* g1    = (const float*)d_in[11];
  const float* be1   = (const float*)d_in[12];
  const float* fw2   = (const float*)d_in[13];
  const float* fb2   = (const float*)d_in[14];
  const float* g2    = (const float*)d_in[15];
  const float* be2   = (const float*)d_in[16];
  const float* fw3   = (const float*)d_in[17];
  const float* fb3   = (const float*)d_in[18];
  float* out = (float*)d_out;

  float* ws      = (float*)d_ws;
  float* hbuf    = ws;                       // 2 * 524288
  float* rows2   = ws + 2*HS;                // 311296
  float* expdt   = rows2 + NPART;            // 1536
  float* agg_tgt = expdt + BS*STEPS*LL;      // 24576
  float* partial = agg_tgt + STEPS*BS*2*EE;  // 8 * 311296

  (void)hipMemsetAsync(hbuf, 0, (size_t)HS * sizeof(float), stream);

  precompute_kernel<<<16, 64, 0, stream>>>(skill, timeq, label, nemb, hbuf, expdt);
  rows2_p1_kernel<<<256, 256, 0, stream>>>(skill, adj, partial);
  rows2_p2_kernel<<<(NPART + 255)/256, 256, 0, stream>>>(partial, rows2);

  for (int t = 0; t < STEPS; ++t) {
    const float* hsrc = hbuf + (size_t)(t & 1) * HS;
    float*       hdst = hbuf + (size_t)((t + 1) & 1) * HS;
    step_kernel<<<512, 256, 0, stream>>>(hsrc, hdst, adj, rows2, expdt, skill,
                                         W1, b1, W2, b2, agg_tgt, t);
  }
  pred_kernel<<<STEPS*BS, 64, 0, stream>>>(agg_tgt, fw1, fb1, g1, be1,
                                           fw2, fb2, g2, be2, fw3, fb3, out);
}